// Round 2
// baseline (266.214 us; speedup 1.0000x reference)
//
#include <hip/hip_runtime.h>

// Head: fused QKV projection + causal attention, MI355X (gfx950)
// B=512, T=256, C=384, D=64. fp32 in/out, bf16 MFMA compute.

typedef short s16x8 __attribute__((ext_vector_type(8)));
typedef float f32x4 __attribute__((ext_vector_type(4)));
typedef unsigned short u16;

__device__ __forceinline__ u16 f2bf(float f) {
  unsigned u = __builtin_bit_cast(unsigned, f);
  u = (u + 0x7fffu + ((u >> 16) & 1u)) >> 16;   // RNE
  return (u16)u;
}

#define MFMA16 __builtin_amdgcn_mfma_f32_16x16x32_bf16

// ---------------------------------------------------------------------------
// Kernel 1: QKV projection. x[131072][384] f32 -> Q,K,V bf16 [512*256][64].
// Structure: full W (192x384 bf16 = 144 KiB) staged in LDS ONCE, then a
// barrier-free streaming loop: A-fragments load global->reg (f32->bf16
// convert in flight, depth-1 prefetch), B-fragments ds_read_b128 from
// swizzled LDS, 24 MFMA per K-chunk per wave (s=2 row-strips share B).
// 512 thr (8 waves), grid 256 = exactly 1 block/CU, wave owns 64 rows.
// ---------------------------------------------------------------------------
__global__ __launch_bounds__(512) void qkv_kernel(
    const float* __restrict__ x,
    const float* __restrict__ WQ, const float* __restrict__ WK,
    const float* __restrict__ WV,
    u16* __restrict__ Qo, u16* __restrict__ Ko, u16* __restrict__ Vo)
{
  __shared__ char wlds[192 * 768];   // 144 KiB: row n (0..191), 384 bf16/row
  const int tid = threadIdx.x;
  const int l  = tid & 63;
  const int w  = tid >> 6;
  const int g  = l >> 4, li = l & 15;

  // ---- stage W once: 192 rows x 48 slots of 8 f32 -> bf16, swizzled ----
#pragma unroll
  for (int i = 0; i < 18; ++i) {
    int id = tid + 512 * i;             // 0..9215
    int row = id / 48, slot = id - row * 48;
    const float* wsrc = (row < 64) ? (WQ + row * 384)
                       : (row < 128) ? (WK + (row - 64) * 384)
                                     : (WV + (row - 128) * 384);
    const float4* src = reinterpret_cast<const float4*>(wsrc + slot * 8);
    float4 a = src[0], b = src[1];
    s16x8 h;
    h[0] = (short)f2bf(a.x); h[1] = (short)f2bf(a.y);
    h[2] = (short)f2bf(a.z); h[3] = (short)f2bf(a.w);
    h[4] = (short)f2bf(b.x); h[5] = (short)f2bf(b.y);
    h[6] = (short)f2bf(b.z); h[7] = (short)f2bf(b.w);
    *reinterpret_cast<s16x8*>(wlds + row * 768 + ((slot ^ (row & 7)) << 4)) = h;
  }
  __syncthreads();

  const long blkbase = (long)blockIdx.x * 512;

  for (int mp = 0; mp < 2; ++mp) {
    const long rowA = blkbase + w * 64 + mp * 32 + li;   // this lane's row, strip A
    const float* pA = x + rowA * 384 + g * 8;
    const float* pB = pA + 16 * 384;                      // strip B = +16 rows

    f32x4 acc[2][12];
#pragma unroll
    for (int s = 0; s < 2; ++s)
#pragma unroll
      for (int nt = 0; nt < 12; ++nt)
        acc[s][nt] = (f32x4){0.f, 0.f, 0.f, 0.f};

    // depth-1 prefetch of kc=0
    float4 a0 = *reinterpret_cast<const float4*>(pA);
    float4 a1 = *reinterpret_cast<const float4*>(pA + 4);
    float4 b0 = *reinterpret_cast<const float4*>(pB);
    float4 b1 = *reinterpret_cast<const float4*>(pB + 4);

#pragma unroll
    for (int kc = 0; kc < 12; ++kc) {
      s16x8 afA, afB;
      afA[0] = (short)f2bf(a0.x); afA[1] = (short)f2bf(a0.y);
      afA[2] = (short)f2bf(a0.z); afA[3] = (short)f2bf(a0.w);
      afA[4] = (short)f2bf(a1.x); afA[5] = (short)f2bf(a1.y);
      afA[6] = (short)f2bf(a1.z); afA[7] = (short)f2bf(a1.w);
      afB[0] = (short)f2bf(b0.x); afB[1] = (short)f2bf(b0.y);
      afB[2] = (short)f2bf(b0.z); afB[3] = (short)f2bf(b0.w);
      afB[4] = (short)f2bf(b1.x); afB[5] = (short)f2bf(b1.y);
      afB[6] = (short)f2bf(b1.z); afB[7] = (short)f2bf(b1.w);
      if (kc < 11) {                     // prefetch next K-chunk
        const float* nA = pA + (kc + 1) * 32;
        const float* nB = pB + (kc + 1) * 32;
        a0 = *reinterpret_cast<const float4*>(nA);
        a1 = *reinterpret_cast<const float4*>(nA + 4);
        b0 = *reinterpret_cast<const float4*>(nB);
        b1 = *reinterpret_cast<const float4*>(nB + 4);
      }
#pragma unroll
      for (int nt = 0; nt < 12; ++nt) {
        int rw = nt * 16 + li;
        s16x8 bf = *reinterpret_cast<const s16x8*>(
            wlds + rw * 768 + (((kc * 4 + g) ^ (rw & 7)) << 4));
        acc[0][nt] = MFMA16(afA, bf, acc[0][nt], 0, 0, 0);
        acc[1][nt] = MFMA16(afB, bf, acc[1][nt], 0, 0, 0);
      }
    }

    // ---- epilogue: C/D layout col=l&15, row=(l>>4)*4+r ----
#pragma unroll
    for (int s = 0; s < 2; ++s) {
      long m = blkbase + w * 64 + mp * 32 + s * 16 + g * 4;
#pragma unroll
      for (int nt = 0; nt < 12; ++nt) {
        int n = nt * 16 + li;
        u16* bp = (n < 64) ? Qo : (n < 128) ? Ko : Vo;
        int d = n & 63;
#pragma unroll
        for (int r = 0; r < 4; ++r)
          bp[(m + r) * 64 + d] = f2bf(acc[s][nt][r]);
      }
    }
  }
}

// ---------------------------------------------------------------------------
// Kernel 2: causal attention, one batch per block, 8 waves of 64 lanes.
// Wave w handles 16-row q-tiles {w, 15-w} -> balanced 5 kv-chunks each.
// LDS: Ksm[256][64] swz (32KB) | Vt[64][256] swz (32KB) | P[wave][16][64] (16KB)
// ---------------------------------------------------------------------------
__global__ __launch_bounds__(512) void attn_kernel(
    const u16* __restrict__ Qw, const u16* __restrict__ Kw,
    const u16* __restrict__ Vw, float* __restrict__ out)
{
  __shared__ char smem[32768 + 32768 + 16384];
  char* Vt = smem + 32768;
  const int tid = threadIdx.x;
  const int l = tid & 63, w = tid >> 6;
  const int g = l >> 4, li = l & 15;
  const long base = (long)blockIdx.x * (256 * 64);

  // ---- stage K (row-major, swizzled) ----
#pragma unroll
  for (int i = 0; i < 4; ++i) {
    int id = tid + 512 * i;                // 2048 chunks
    int row = id >> 3, slot = id & 7;
    s16x8 v = *reinterpret_cast<const s16x8*>(Kw + base + row * 64 + slot * 8);
    *reinterpret_cast<s16x8*>(smem + row * 128 + ((slot ^ (row & 7)) << 4)) = v;
  }
  // ---- stage V transposed: Vt[d][kv], swizzled ----
#pragma unroll
  for (int i = 0; i < 4; ++i) {
    int id = tid + 512 * i;
    int row = id >> 3, slot = id & 7;
    s16x8 v = *reinterpret_cast<const s16x8*>(Vw + base + row * 64 + slot * 8);
#pragma unroll
    for (int j = 0; j < 8; ++j) {
      int d = slot * 8 + j;
      *reinterpret_cast<u16*>(Vt + d * 512 + ((row * 2) ^ ((d & 7) << 4))) =
          (u16)(unsigned short)v[j];
    }
  }
  __syncthreads();

  char* Pw = smem + 65536 + w * 2048;      // per-wave P buffer [16][64] bf16

  for (int half = 0; half < 2; ++half) {
    const int qt = half ? (15 - w) : w;
    s16x8 qf[2];
#pragma unroll
    for (int dk = 0; dk < 2; ++dk)
      qf[dk] = *reinterpret_cast<const s16x8*>(
          Qw + base + (qt * 16 + li) * 64 + dk * 32 + g * 8);

    f32x4 o[4];
    float m[4], lsum[4];
#pragma unroll
    for (int r = 0; r < 4; ++r) { m[r] = -1e30f; lsum[r] = 0.f; }
#pragma unroll
    for (int nd = 0; nd < 4; ++nd) o[nd] = (f32x4){0.f, 0.f, 0.f, 0.f};

    const int nc = (qt >> 2) + 1;
    for (int c = 0; c < nc; ++c) {
      // ---- S = Q K^T ----
      f32x4 s[4];
#pragma unroll
      for (int nj = 0; nj < 4; ++nj) s[nj] = (f32x4){0.f, 0.f, 0.f, 0.f};
#pragma unroll
      for (int dk = 0; dk < 2; ++dk) {
#pragma unroll
        for (int nj = 0; nj < 4; ++nj) {
          int rb = c * 64 + nj * 16 + li;
          s16x8 kf = *reinterpret_cast<const s16x8*>(
              smem + rb * 128 + (((dk * 4 + g) ^ (rb & 7)) << 4));
          s[nj] = MFMA16(qf[dk], kf, s[nj], 0, 0, 0);
        }
      }
      const bool last = (c == nc - 1);
      // ---- scale + causal mask ----
#pragma unroll
      for (int nj = 0; nj < 4; ++nj)
#pragma unroll
        for (int r = 0; r < 4; ++r) {
          float v = s[nj][r] * 0.125f;
          if (last && (c * 64 + nj * 16 + li) > (qt * 16 + g * 4 + r)) v = -1e30f;
          s[nj][r] = v;
        }
      // ---- online max ----
      float alpha[4];
#pragma unroll
      for (int r = 0; r < 4; ++r) {
        float pm = fmaxf(fmaxf(s[0][r], s[1][r]), fmaxf(s[2][r], s[3][r]));
        pm = fmaxf(pm, __shfl_xor(pm, 1));
        pm = fmaxf(pm, __shfl_xor(pm, 2));
        pm = fmaxf(pm, __shfl_xor(pm, 4));
        pm = fmaxf(pm, __shfl_xor(pm, 8));
        float mn = fmaxf(m[r], pm);
        alpha[r] = __expf(m[r] - mn);
        m[r] = mn;
      }
      // ---- P = exp(S-m), write bf16 to per-wave LDS (swizzled) ----
      float psum[4] = {0.f, 0.f, 0.f, 0.f};
#pragma unroll
      for (int nj = 0; nj < 4; ++nj)
#pragma unroll
        for (int r = 0; r < 4; ++r) {
          float p = __expf(s[nj][r] - m[r]);
          psum[r] += p;
          int row = g * 4 + r;
          *reinterpret_cast<u16*>(
              Pw + row * 128 + ((nj * 32 + li * 2) ^ ((row & 7) << 4))) = f2bf(p);
        }
#pragma unroll
      for (int r = 0; r < 4; ++r) {
        float ps = psum[r];
        ps += __shfl_xor(ps, 1);
        ps += __shfl_xor(ps, 2);
        ps += __shfl_xor(ps, 4);
        ps += __shfl_xor(ps, 8);
        lsum[r] = lsum[r] * alpha[r] + ps;
      }
#pragma unroll
      for (int nd = 0; nd < 4; ++nd)
#pragma unroll
        for (int r = 0; r < 4; ++r) o[nd][r] *= alpha[r];

      __asm__ volatile("s_waitcnt lgkmcnt(0)" ::: "memory");
      // ---- O += P V ----
      s16x8 pa[2];
#pragma unroll
      for (int kk = 0; kk < 2; ++kk)
        pa[kk] = *reinterpret_cast<const s16x8*>(
            Pw + li * 128 + (((kk * 4 + g) ^ (li & 7)) << 4));
#pragma unroll
      for (int nd = 0; nd < 4; ++nd) {
#pragma unroll
        for (int kk = 0; kk < 2; ++kk) {
          int d = nd * 16 + li;
          s16x8 vf = *reinterpret_cast<const s16x8*>(
              Vt + d * 512 + ((c * 128 + kk * 64 + g * 16) ^ ((d & 7) << 4)));
          o[nd] = MFMA16(pa[kk], vf, o[nd], 0, 0, 0);
        }
      }
    }
    // ---- epilogue ----
#pragma unroll
    for (int r = 0; r < 4; ++r) lsum[r] = 1.f / lsum[r];
#pragma unroll
    for (int nd = 0; nd < 4; ++nd)
#pragma unroll
      for (int r = 0; r < 4; ++r)
        out[base + (qt * 16 + g * 4 + r) * 64 + nd * 16 + li] = o[nd][r] * lsum[r];
  }
}

extern "C" void kernel_launch(void* const* d_in, const int* in_sizes, int n_in,
                              void* d_out, int out_size, void* d_ws, size_t ws_size,
                              hipStream_t stream) {
  const float* x  = (const float*)d_in[0];
  const float* WQ = (const float*)d_in[1];
  const float* WK = (const float*)d_in[2];
  const float* WV = (const float*)d_in[3];
  float* out = (float*)d_out;

  // workspace: Q | K | V bf16, each 512*256*64 elems = 16 MiB
  char* ws = (char*)d_ws;
  u16* Qo = (u16*)(ws);
  u16* Ko = (u16*)(ws + 16777216);
  u16* Vo = (u16*)(ws + 2 * 16777216);

  qkv_kernel<<<dim3(256), dim3(512), 0, stream>>>(x, WQ, WK, WV, Qo, Ko, Vo);
  attn_kernel<<<dim3(512), dim3(512), 0, stream>>>(Qo, Ko, Vo, out);
}

// Round 3
// 168.922 us; speedup vs baseline: 1.5760x; 1.5760x over previous
//
#include <hip/hip_runtime.h>

// Head: fused QKV projection + causal attention, MI355X (gfx950)
// B=512, T=256, C=384, D=64. fp32 in/out, bf16 MFMA compute.

typedef short s16x8 __attribute__((ext_vector_type(8)));
typedef float f32x4 __attribute__((ext_vector_type(4)));
typedef unsigned short u16;
typedef unsigned short u16x4 __attribute__((ext_vector_type(4)));

__device__ __forceinline__ u16 f2bf(float f) {
  unsigned u = __builtin_bit_cast(unsigned, f);
  u = (u + 0x7fffu + ((u >> 16) & 1u)) >> 16;   // RNE
  return (u16)u;
}

__device__ __forceinline__ s16x8 pack8(float4 a, float4 b) {
  s16x8 h;
  h[0] = (short)f2bf(a.x); h[1] = (short)f2bf(a.y);
  h[2] = (short)f2bf(a.z); h[3] = (short)f2bf(a.w);
  h[4] = (short)f2bf(b.x); h[5] = (short)f2bf(b.y);
  h[6] = (short)f2bf(b.z); h[7] = (short)f2bf(b.w);
  return h;
}

#define MFMA16 __builtin_amdgcn_mfma_f32_16x16x32_bf16

// ---------------------------------------------------------------------------
// Kernel 1: QKV projection. x[131072][384] f32 -> Q,K,V bf16 [131072][64].
// Zero LDS, zero barriers. 256 thr = 4 waves; wave w owns output cols
// [48w, 48w+48) as MFMA *A*-operand W-fragments held in registers
// (3 tiles x 12 kc x 4 VGPR = 144 VGPR, loaded once; W is L2-resident).
// Block streams 256 x-rows as 16 strips of 16; per kc one 32B/lane x-load
// (f32->bf16 in flight, depth-2 pipeline) feeds 3 MFMAs. C/D layout:
// col=lane&15 <-> x-row (the row this lane loaded), row=g*4+r <-> output n.
// Grid 512 = 2 blocks/CU; launch_bounds caps VGPR at 256 (no spill).
// ---------------------------------------------------------------------------
__global__ __launch_bounds__(256, 2) void qkv_kernel(
    const float* __restrict__ x,
    const float* __restrict__ WQ, const float* __restrict__ WK,
    const float* __restrict__ WV,
    u16* __restrict__ Qo, u16* __restrict__ Ko, u16* __restrict__ Vo)
{
  const int tid = threadIdx.x;
  const int l  = tid & 63;
  const int w  = tid >> 6;
  const int g  = l >> 4, li = l & 15;
  const int nb0 = w * 48;                 // wave's output-col base

  // ---- load W fragments into registers (once) ----
  s16x8 wf[3][12];
#pragma unroll
  for (int t = 0; t < 3; ++t) {
    const int nb = nb0 + t * 16;
    const float* wsrc = ((nb < 64) ? (WQ + nb * 384)
                        : (nb < 128) ? (WK + (nb - 64) * 384)
                                     : (WV + (nb - 128) * 384))
                        + li * 384 + g * 8;
#pragma unroll
    for (int kc = 0; kc < 12; ++kc) {
      float4 a = *reinterpret_cast<const float4*>(wsrc + kc * 32);
      float4 b = *reinterpret_cast<const float4*>(wsrc + kc * 32 + 4);
      wf[t][kc] = pack8(a, b);
    }
  }

  const long rowbase = (long)blockIdx.x * 256;

#pragma unroll 1
  for (int sp = 0; sp < 16; ++sp) {
    const long mrow = rowbase + sp * 16 + li;
    const float* px = x + mrow * 384 + g * 8;

    f32x4 acc0 = (f32x4){0.f,0.f,0.f,0.f};
    f32x4 acc1 = (f32x4){0.f,0.f,0.f,0.f};
    f32x4 acc2 = (f32x4){0.f,0.f,0.f,0.f};

    // depth-2 pipeline
    float4 a0 = *reinterpret_cast<const float4*>(px);
    float4 a1 = *reinterpret_cast<const float4*>(px + 4);
    float4 b0 = *reinterpret_cast<const float4*>(px + 32);
    float4 b1 = *reinterpret_cast<const float4*>(px + 36);

#pragma unroll
    for (int kc = 0; kc < 12; ++kc) {
      s16x8 xf = pack8(a0, a1);
      a0 = b0; a1 = b1;
      if (kc < 10) {
        b0 = *reinterpret_cast<const float4*>(px + (kc + 2) * 32);
        b1 = *reinterpret_cast<const float4*>(px + (kc + 2) * 32 + 4);
      }
      acc0 = MFMA16(wf[0][kc], xf, acc0, 0, 0, 0);
      acc1 = MFMA16(wf[1][kc], xf, acc1, 0, 0, 0);
      acc2 = MFMA16(wf[2][kc], xf, acc2, 0, 0, 0);
    }

    // ---- store: lane writes 4 consecutive output dims of its own row ----
    f32x4 accs[3] = {acc0, acc1, acc2};
#pragma unroll
    for (int t = 0; t < 3; ++t) {
      const int nb = nb0 + t * 16 + g * 4;
      u16* bp = (nb < 64) ? Qo : (nb < 128) ? Ko : Vo;
      const int d = nb & 63;
      u16x4 pk;
      pk[0] = f2bf(accs[t][0]); pk[1] = f2bf(accs[t][1]);
      pk[2] = f2bf(accs[t][2]); pk[3] = f2bf(accs[t][3]);
      *reinterpret_cast<u16x4*>(bp + mrow * 64 + d) = pk;
    }
  }
}

// ---------------------------------------------------------------------------
// Kernel 2: causal attention, one batch per block, 8 waves of 64 lanes.
// Wave w handles 16-row q-tiles {w, 15-w} -> balanced 5 kv-chunks each.
// LDS: Ksm[256][64] swz (32KB) | Vt[64][256] swz (32KB) | P[wave][16][64] (16KB)
// ---------------------------------------------------------------------------
__global__ __launch_bounds__(512) void attn_kernel(
    const u16* __restrict__ Qw, const u16* __restrict__ Kw,
    const u16* __restrict__ Vw, float* __restrict__ out)
{
  __shared__ char smem[32768 + 32768 + 16384];
  char* Vt = smem + 32768;
  const int tid = threadIdx.x;
  const int l = tid & 63, w = tid >> 6;
  const int g = l >> 4, li = l & 15;
  const long base = (long)blockIdx.x * (256 * 64);

  // ---- stage K (row-major, swizzled) ----
#pragma unroll
  for (int i = 0; i < 4; ++i) {
    int id = tid + 512 * i;                // 2048 chunks
    int row = id >> 3, slot = id & 7;
    s16x8 v = *reinterpret_cast<const s16x8*>(Kw + base + row * 64 + slot * 8);
    *reinterpret_cast<s16x8*>(smem + row * 128 + ((slot ^ (row & 7)) << 4)) = v;
  }
  // ---- stage V transposed: Vt[d][kv], swizzled ----
#pragma unroll
  for (int i = 0; i < 4; ++i) {
    int id = tid + 512 * i;
    int row = id >> 3, slot = id & 7;
    s16x8 v = *reinterpret_cast<const s16x8*>(Vw + base + row * 64 + slot * 8);
#pragma unroll
    for (int j = 0; j < 8; ++j) {
      int d = slot * 8 + j;
      *reinterpret_cast<u16*>(Vt + d * 512 + ((row * 2) ^ ((d & 7) << 4))) =
          (u16)(unsigned short)v[j];
    }
  }
  __syncthreads();

  char* Pw = smem + 65536 + w * 2048;      // per-wave P buffer [16][64] bf16

  for (int half = 0; half < 2; ++half) {
    const int qt = half ? (15 - w) : w;
    s16x8 qf[2];
#pragma unroll
    for (int dk = 0; dk < 2; ++dk)
      qf[dk] = *reinterpret_cast<const s16x8*>(
          Qw + base + (qt * 16 + li) * 64 + dk * 32 + g * 8);

    f32x4 o[4];
    float m[4], lsum[4];
#pragma unroll
    for (int r = 0; r < 4; ++r) { m[r] = -1e30f; lsum[r] = 0.f; }
#pragma unroll
    for (int nd = 0; nd < 4; ++nd) o[nd] = (f32x4){0.f, 0.f, 0.f, 0.f};

    const int nc = (qt >> 2) + 1;
    for (int c = 0; c < nc; ++c) {
      // ---- S = Q K^T ----
      f32x4 s[4];
#pragma unroll
      for (int nj = 0; nj < 4; ++nj) s[nj] = (f32x4){0.f, 0.f, 0.f, 0.f};
#pragma unroll
      for (int dk = 0; dk < 2; ++dk) {
#pragma unroll
        for (int nj = 0; nj < 4; ++nj) {
          int rb = c * 64 + nj * 16 + li;
          s16x8 kf = *reinterpret_cast<const s16x8*>(
              smem + rb * 128 + (((dk * 4 + g) ^ (rb & 7)) << 4));
          s[nj] = MFMA16(qf[dk], kf, s[nj], 0, 0, 0);
        }
      }
      const bool last = (c == nc - 1);
      // ---- scale + causal mask ----
#pragma unroll
      for (int nj = 0; nj < 4; ++nj)
#pragma unroll
        for (int r = 0; r < 4; ++r) {
          float v = s[nj][r] * 0.125f;
          if (last && (c * 64 + nj * 16 + li) > (qt * 16 + g * 4 + r)) v = -1e30f;
          s[nj][r] = v;
        }
      // ---- online max ----
      float alpha[4];
#pragma unroll
      for (int r = 0; r < 4; ++r) {
        float pm = fmaxf(fmaxf(s[0][r], s[1][r]), fmaxf(s[2][r], s[3][r]));
        pm = fmaxf(pm, __shfl_xor(pm, 1));
        pm = fmaxf(pm, __shfl_xor(pm, 2));
        pm = fmaxf(pm, __shfl_xor(pm, 4));
        pm = fmaxf(pm, __shfl_xor(pm, 8));
        float mn = fmaxf(m[r], pm);
        alpha[r] = __expf(m[r] - mn);
        m[r] = mn;
      }
      // ---- P = exp(S-m), write bf16 to per-wave LDS (swizzled) ----
      float psum[4] = {0.f, 0.f, 0.f, 0.f};
#pragma unroll
      for (int nj = 0; nj < 4; ++nj)
#pragma unroll
        for (int r = 0; r < 4; ++r) {
          float p = __expf(s[nj][r] - m[r]);
          psum[r] += p;
          int row = g * 4 + r;
          *reinterpret_cast<u16*>(
              Pw + row * 128 + ((nj * 32 + li * 2) ^ ((row & 7) << 4))) = f2bf(p);
        }
#pragma unroll
      for (int r = 0; r < 4; ++r) {
        float ps = psum[r];
        ps += __shfl_xor(ps, 1);
        ps += __shfl_xor(ps, 2);
        ps += __shfl_xor(ps, 4);
        ps += __shfl_xor(ps, 8);
        lsum[r] = lsum[r] * alpha[r] + ps;
      }
#pragma unroll
      for (int nd = 0; nd < 4; ++nd)
#pragma unroll
        for (int r = 0; r < 4; ++r) o[nd][r] *= alpha[r];

      __asm__ volatile("s_waitcnt lgkmcnt(0)" ::: "memory");
      // ---- O += P V ----
      s16x8 pa[2];
#pragma unroll
      for (int kk = 0; kk < 2; ++kk)
        pa[kk] = *reinterpret_cast<const s16x8*>(
            Pw + li * 128 + (((kk * 4 + g) ^ (li & 7)) << 4));
#pragma unroll
      for (int nd = 0; nd < 4; ++nd) {
#pragma unroll
        for (int kk = 0; kk < 2; ++kk) {
          int d = nd * 16 + li;
          s16x8 vf = *reinterpret_cast<const s16x8*>(
              Vt + d * 512 + ((c * 128 + kk * 64 + g * 16) ^ ((d & 7) << 4)));
          o[nd] = MFMA16(pa[kk], vf, o[nd], 0, 0, 0);
        }
      }
    }
    // ---- epilogue ----
#pragma unroll
    for (int r = 0; r < 4; ++r) lsum[r] = 1.f / lsum[r];
#pragma unroll
    for (int nd = 0; nd < 4; ++nd)
#pragma unroll
      for (int r = 0; r < 4; ++r)
        out[base + (qt * 16 + g * 4 + r) * 64 + nd * 16 + li] = o[nd][r] * lsum[r];
  }
}

extern "C" void kernel_launch(void* const* d_in, const int* in_sizes, int n_in,
                              void* d_out, int out_size, void* d_ws, size_t ws_size,
                              hipStream_t stream) {
  const float* x  = (const float*)d_in[0];
  const float* WQ = (const float*)d_in[1];
  const float* WK = (const float*)d_in[2];
  const float* WV = (const float*)d_in[3];
  float* out = (float*)d_out;

  // workspace: Q | K | V bf16, each 512*256*64 elems = 16 MiB
  char* ws = (char*)d_ws;
  u16* Qo = (u16*)(ws);
  u16* Ko = (u16*)(ws + 16777216);
  u16* Vo = (u16*)(ws + 2 * 16777216);

  qkv_kernel<<<dim3(512), dim3(256), 0, stream>>>(x, WQ, WK, WV, Qo, Ko, Vo);
  attn_kernel<<<dim3(512), dim3(512), 0, stream>>>(Qo, Ko, Vo, out);
}